// Round 4
// baseline (3225.718 us; speedup 1.0000x reference)
//
#include <hip/hip_runtime.h>

// KMeans predict — EMULATE the fp32 numpy/BLAS reference bit-for-bit.
//   c_sq  = np.sum(c*c, -1)            : numpy pairwise fp32 (exact emulation)
//   dot   = sgemm fp32                 : sequential FMA over d, kc=384 panels,
//                                        one merge add between panels
//   score = (-2*dot) + c_sq            : *(-2) exact, one rounded add
//   out   = argmin, first-index ties   : strict '<', ascending k
// N=131072, D=768, K=1024, fp32 in, int32 out.

#define N_TOK 131072
#define DIMS  768
#define KCL   1024
#define TM    64     // tokens per block
#define TN    128    // clusters per chunk
#define BK    32     // D chunk
#define KC    384    // BLAS panel split: dot = chain(0..383) + chain(384..767)
#define XSTRIDE 68   // 64+4: rows 16B-aligned, breaks pow2 bank stride
#define CSTRIDE 132  // 128+4
#define THREADS 256

// ---- numpy pairwise fp32 sum of squares, bit-exact -------------------------
// numpy pairwise_sum: n=768 -> 384+384 -> 192+192 -> 96+96; 96<=128 is the
// 8-accumulator base case; combine ((r0+r1)+(r2+r3))+((r4+r5)+(r6+r7)).
__global__ void csq_np_kernel(const float* __restrict__ c, float* __restrict__ csq) {
    const int k = blockIdx.x * blockDim.x + threadIdx.x;
    if (k >= KCL) return;
    const float* row = c + (size_t)k * DIMS;
    float bsum[8];
    #pragma unroll
    for (int b = 0; b < 8; ++b) {
        const float* a = row + b * 96;
        float r[8];
        #pragma unroll
        for (int j = 0; j < 8; ++j) { const float v = a[j]; r[j] = __fmul_rn(v, v); }
        for (int i = 8; i < 96; i += 8) {
            #pragma unroll
            for (int j = 0; j < 8; ++j) {
                const float v = a[i + j];
                r[j] = __fadd_rn(r[j], __fmul_rn(v, v));
            }
        }
        bsum[b] = __fadd_rn(__fadd_rn(__fadd_rn(r[0], r[1]), __fadd_rn(r[2], r[3])),
                            __fadd_rn(__fadd_rn(r[4], r[5]), __fadd_rn(r[6], r[7])));
    }
    const float s1 = __fadd_rn(__fadd_rn(bsum[0], bsum[1]), __fadd_rn(bsum[2], bsum[3]));
    const float s2 = __fadd_rn(__fadd_rn(bsum[4], bsum[5]), __fadd_rn(bsum[6], bsum[7]));
    csq[k] = __fadd_rn(s1, s2);
}

// ---- main GEMM + argmin, ref-rounding-faithful -----------------------------
__launch_bounds__(THREADS, 2)
__global__ void kmeans_em_kernel(const float* __restrict__ x,
                                 const float* __restrict__ cent,
                                 const float* __restrict__ csq,
                                 int* __restrict__ out) {
    __shared__ __align__(16) float smem[BK * XSTRIDE + BK * CSTRIDE];
    float* Xs = smem;                // [BK][XSTRIDE]  (d-major, token minor)
    float* Cs = smem + BK * XSTRIDE; // [BK][CSTRIDE]

    const int tid = threadIdx.x;
    const int tx  = tid & 15;   // cluster group: 8 clusters
    const int ty  = tid >> 4;   // token group: 4 tokens
    const int m0  = blockIdx.x * TM;
    const int c4  = tid & 7;    // float4 index along D-chunk
    const int r0  = tid >> 3;   // row 0..31

    float b1[4];
    int   i1[4];
    #pragma unroll
    for (int i = 0; i < 4; ++i) { b1[i] = 3.0e38f; i1[i] = 0; }

    for (int nt = 0; nt < KCL; nt += TN) {
        float acc[4][8];    // running FMA chain (current panel)
        float acc1[4][8];   // completed first panel (d=0..KC-1)
        #pragma unroll
        for (int i = 0; i < 4; ++i)
            #pragma unroll
            for (int j = 0; j < 8; ++j) acc[i][j] = 0.0f;

        for (int db = 0; db < DIMS; db += BK) {
            if (db == KC) {   // BLAS panel boundary: save chain 1, restart
                #pragma unroll
                for (int i = 0; i < 4; ++i)
                    #pragma unroll
                    for (int j = 0; j < 8; ++j) { acc1[i][j] = acc[i][j]; acc[i][j] = 0.0f; }
            }
            // ---- stage X tile: 64 rows x BK, transposed into Xs[d][m] ----
            #pragma unroll
            for (int p = 0; p < 2; ++p) {
                const int r = r0 + p * 32;
                const float4 v = *(const float4*)(x + (size_t)(m0 + r) * DIMS + db + c4 * 4);
                Xs[(c4 * 4 + 0) * XSTRIDE + r] = v.x;
                Xs[(c4 * 4 + 1) * XSTRIDE + r] = v.y;
                Xs[(c4 * 4 + 2) * XSTRIDE + r] = v.z;
                Xs[(c4 * 4 + 3) * XSTRIDE + r] = v.w;
            }
            // ---- stage C tile: 128 rows x BK, transposed into Cs[d][n] ----
            #pragma unroll
            for (int p = 0; p < 4; ++p) {
                const int r = r0 + p * 32;
                const float4 v = *(const float4*)(cent + (size_t)(nt + r) * DIMS + db + c4 * 4);
                Cs[(c4 * 4 + 0) * CSTRIDE + r] = v.x;
                Cs[(c4 * 4 + 1) * CSTRIDE + r] = v.y;
                Cs[(c4 * 4 + 2) * CSTRIDE + r] = v.z;
                Cs[(c4 * 4 + 3) * CSTRIDE + r] = v.w;
            }
            __syncthreads();

            // ---- MAC: strictly ascending d, one fp32 FMA chain/element ----
            #pragma unroll 8
            for (int d = 0; d < BK; ++d) {
                const float4 a  = *(const float4*)&Xs[d * XSTRIDE + ty * 4];
                const float4 b0 = *(const float4*)&Cs[d * CSTRIDE + tx * 8];
                const float4 bq = *(const float4*)&Cs[d * CSTRIDE + tx * 8 + 4];
                const float av[4] = {a.x, a.y, a.z, a.w};
                const float bv[8] = {b0.x, b0.y, b0.z, b0.w, bq.x, bq.y, bq.z, bq.w};
                #pragma unroll
                for (int i = 0; i < 4; ++i)
                    #pragma unroll
                    for (int j = 0; j < 8; ++j)
                        acc[i][j] = __fmaf_rn(av[i], bv[j], acc[i][j]);
            }
            __syncthreads();
        }

        // ---- epilogue: score = (-2*dot) + c_sq; argmin, first-index ----
        #pragma unroll
        for (int j = 0; j < 8; ++j) {
            const int   k  = nt + tx * 8 + j;
            const float cq = csq[k];
            #pragma unroll
            for (int i = 0; i < 4; ++i) {
                const float dot = __fadd_rn(acc1[i][j], acc[i][j]);   // panel merge
                const float sc  = __fadd_rn(__fmul_rn(-2.0f, dot), cq);
                if (sc < b1[i]) { b1[i] = sc; i1[i] = k; }            // strict <
            }
        }
    }

    // ---- cross-thread argmin merge (16 tx groups per token) ----
    __syncthreads();  // tile buffers dead; overlay reduction arrays
    float* rv = smem;                   // [64][17]
    int*   ri = (int*)(smem + TM * 17); // [64][17]
    #pragma unroll
    for (int i = 0; i < 4; ++i) {
        rv[(ty * 4 + i) * 17 + tx] = b1[i];
        ri[(ty * 4 + i) * 17 + tx] = i1[i];
    }
    __syncthreads();
    if (tid < TM) {
        float B = rv[tid * 17];
        int   I = ri[tid * 17];
        #pragma unroll
        for (int t = 1; t < 16; ++t) {
            const float v  = rv[tid * 17 + t];
            const int   ix = ri[tid * 17 + t];
            if (v < B || (v == B && ix < I)) { B = v; I = ix; }
        }
        out[m0 + tid] = I;
    }
}

extern "C" void kernel_launch(void* const* d_in, const int* in_sizes, int n_in,
                              void* d_out, int out_size, void* d_ws, size_t ws_size,
                              hipStream_t stream) {
    const float* x    = (const float*)d_in[0];
    const float* cent = (const float*)d_in[1];
    float* csq = (float*)d_ws;      // 1024 floats scratch
    int*   out = (int*)d_out;

    csq_np_kernel<<<(KCL + 255) / 256, 256, 0, stream>>>(cent, csq);
    kmeans_em_kernel<<<N_TOK / TM, THREADS, 0, stream>>>(x, cent, csq, out);
}